// Round 12
// baseline (144.588 us; speedup 1.0000x reference)
//
#include <hip/hip_runtime.h>
#include <math.h>

typedef __attribute__((ext_vector_type(8))) short short8;
typedef __attribute__((ext_vector_type(4))) float f32x4;
typedef __attribute__((ext_vector_type(16))) float f32x16;

#define NTAP 125
#define DCH 32

static __device__ __forceinline__ unsigned short f2bf(float f) {
    union { float f; unsigned u; } v; v.f = f;
    unsigned u = v.u;
    return (unsigned short)((u + 0x7FFFu + ((u >> 16) & 1u)) >> 16);
}

static __device__ __forceinline__ void gld_lds16(const void* g, void* l) {
    __builtin_amdgcn_global_load_lds(
        (const __attribute__((address_space(1))) unsigned int*)g,
        (__attribute__((address_space(3))) unsigned int*)l, 16, 0, 0);
}

// ---------------------------------------------------------------------------
// Kernel 1 (fused build+pack): build conv weights for tap t in LDS, then
// pack to bf16 B-fragments kwb[tap][kh][lane][8] for mfma_f32_32x32x16_bf16.
// Skip connection folded into center tap 62. Block 0 also fills the 4 KB
// zero-page. (math verified R0-R11)
// ---------------------------------------------------------------------------
__global__ __launch_bounds__(128) void build_pack(
    const float* __restrict__ weight,
    const float* __restrict__ w_sc0,
    const float* __restrict__ w_sc1,
    unsigned short* __restrict__ kwb,
    float4* __restrict__ zpg)
{
    const int t = blockIdx.x;
    if (t == 0) {
        float4 z4 = make_float4(0.f, 0.f, 0.f, 0.f);
        zpg[threadIdx.x * 2] = z4;
        zpg[threadIdx.x * 2 + 1] = z4;
    }
    const int dx = t / 25, dy = (t / 5) % 5, dz = t % 5;
    const float px = dx - 2.0f, py = dy - 2.0f, pz = dz - 2.0f;
    const float d = sqrtf(px * px + py * py + pz * pz);

    const float stepv = 2.5f / 6.0f;
    const float embc = 1.14136f * expf(2.0f);
    float emb[5];
#pragma unroll
    for (int n = 0; n < 5; ++n) {
        float diff = (d - stepv * (float)(n + 1)) / stepv;
        float a = diff + 1.0f, bb = 1.0f - diff;
        float v = 0.0f;
        if (a > 0.0f && bb > 0.0f)
            v = embc * expf(-1.0f / a) * expf(-1.0f / bb);
        emb[n] = v;
    }

    const float inv_d = (d > 0.0f) ? 1.0f / d : 0.0f;
    const float ux = px * inv_d, uy = py * inv_d, uz = pz * inv_d;
    const float s3 = 1.73205081f, s5 = 2.23606798f, s15 = 3.87298335f;
    float sh[9];
    sh[0] = 1.0f;
    sh[1] = s3 * ux; sh[2] = s3 * uy; sh[3] = s3 * uz;
    sh[4] = s15 * ux * uz;
    sh[5] = s15 * ux * uy;
    sh[6] = s5 * (uy * uy - 0.5f * (ux * ux + uz * uz));
    sh[7] = s15 * uy * uz;
    sh[8] = 0.5f * s15 * (uz * uz - ux * ux);

    const float i_s2 = 0.70710678f, i_s6 = 0.40824829f, i_s5 = 0.44721360f;
    float T[3][3];
    T[0][0] = i_s5 * (-sh[6] * i_s6 - sh[8] * i_s2);
    T[0][1] = i_s5 * (sh[5] * i_s2);
    T[0][2] = i_s5 * (sh[4] * i_s2);
    T[1][0] = T[0][1];
    T[1][1] = i_s5 * (2.0f * sh[6] * i_s6);
    T[1][2] = i_s5 * (sh[7] * i_s2);
    T[2][0] = T[0][2];
    T[2][1] = T[1][2];
    T[2][2] = i_s5 * (-sh[6] * i_s6 + sh[8] * i_s2);

    __shared__ float Wt[320];
    __shared__ float kws[1024];              // [ci=32][co=32] for this tap
    for (int col = threadIdx.x; col < 320; col += 128) {
        float a = 0.0f;
#pragma unroll
        for (int n = 0; n < 5; ++n) a += emb[n] * weight[n * 320 + col];
        Wt[col] = a * (1.0f / 125.0f);
    }
    __syncthreads();

    const float pw0 = 0.25f;
    const float pw1 = 0.35355339f;
    const float inv_s3 = 0.57735027f;
    const float inv_s8 = 0.35355339f;

    for (int idx = threadIdx.x; idx < 1024; idx += 128) {
        const int o = idx >> 5, i = idx & 31;
        float val;
        if (o < 8) {
            if (i < 8) {
                val = pw0 * Wt[i * 8 + o];
            } else {
                const int u = (i - 8) / 3, m = (i - 8) % 3;
                val = pw0 * inv_s3 * Wt[192 + u * 8 + o] * sh[1 + m];
            }
        } else {
            const int v = (o - 8) / 3, k = (o - 8) % 3;
            if (i < 8) {
                val = pw1 * inv_s3 * Wt[64 + i * 8 + v] * sh[1 + k];
            } else {
                const int u = (i - 8) / 3, m = (i - 8) % 3;
                float tv = Wt[256 + u * 8 + v] * T[m][k];
                if (m == k) tv += inv_s3 * Wt[128 + u * 8 + v];
                val = pw1 * tv;
            }
        }
        if (t == 62) {
            if (o < 8 && i < 8) {
                val += inv_s8 * w_sc0[i * 8 + o];
            } else if (o >= 8 && i >= 8) {
                const int u = (i - 8) / 3, m = (i - 8) % 3;
                const int v = (o - 8) / 3, k = (o - 8) % 3;
                if (m == k) val += inv_s8 * w_sc1[u * 8 + v];
            }
        }
        kws[i * 32 + o] = val;
    }
    __syncthreads();

    // pack: kwb[tap][kh][lane][8], ci = kh*16 + (l>>5)*8 + j, co = l&31
    const int tid = threadIdx.x;
    const int kh = tid >> 6, l = tid & 63;
    const int co = l & 31;
    const int cib = kh * 16 + (l >> 5) * 8;
    unsigned short v[8];
#pragma unroll
    for (int j = 0; j < 8; ++j)
        v[j] = f2bf(kws[(cib + j) * 32 + co]);
    uint4 o;
    o.x = (unsigned)v[0] | ((unsigned)v[1] << 16);
    o.y = (unsigned)v[2] | ((unsigned)v[3] << 16);
    o.z = (unsigned)v[4] | ((unsigned)v[5] << 16);
    o.w = (unsigned)v[6] | ((unsigned)v[7] << 16);
    *reinterpret_cast<uint4*>(kwb + ((size_t)(t * 2 + kh) * 64 + l) * 8) = o;
}

// ---------------------------------------------------------------------------
// Kernel 2: transpose x fp32 [b][ci][X][Y][Z] -> bf16 xt[b][64][64][68][32]
// with z-halo of 2 each side (z_idx = z + 2), halo zero-filled here.
// (verified passing in R5/R10, absmax 0.03125)
// ---------------------------------------------------------------------------
__global__ __launch_bounds__(256) void xpose(
    const float* __restrict__ x, unsigned short* __restrict__ xt)
{
    const int xx = blockIdx.x, yy = blockIdx.y, b = blockIdx.z;
    const int t = threadIdx.x;
    const int z = t & 63, part = t >> 6;
    const float* src = x + ((((size_t)b * 32) * 64 + xx) * 64 + yy) * 64 + z;
    unsigned short v[8];
#pragma unroll
    for (int j = 0; j < 8; ++j)
        v[j] = f2bf(src[(size_t)(part * 8 + j) * 262144]);
    uint4 o;
    o.x = (unsigned)v[0] | ((unsigned)v[1] << 16);
    o.y = (unsigned)v[2] | ((unsigned)v[3] << 16);
    o.z = (unsigned)v[4] | ((unsigned)v[5] << 16);
    o.w = (unsigned)v[6] | ((unsigned)v[7] << 16);
    unsigned short* row =
        xt + (((size_t)b * 64 + xx) * 64 + yy) * 2176;   // 68*32 shorts/row
    *reinterpret_cast<uint4*>(row + (size_t)(z + 2) * 32 + part * 8) = o;
    if (t < 16) {
        const int zi = t >> 2;                     // 0..3
        const int z_idx = (zi < 2) ? zi : 64 + zi; // 0,1,66,67
        uint4 zz; zz.x = zz.y = zz.z = zz.w = 0u;
        *reinterpret_cast<uint4*>(row + (size_t)z_idx * 32 + (t & 3) * 8) = zz;
    }
}

// ---------------------------------------------------------------------------
// Kernel 3: implicit-GEMM conv via mfma_f32_32x32x16_bf16.
// R12: WAVE-PRIVATE slab staging -> ZERO per-step barriers.
// R0-R11 evidence: all schedule variants pinned at ~7600 cyc/step because
// per-step global barriers re-synchronize the 8 waves 40x, making the two
// waves on each SIMD alternate (sum) instead of overlap. The barrier
// existed only because slab staging was block-shared. Here each wave
// stages ITS OWN A-footprint (rows oyp*2..+1, slots zh*32+l31+dz ->
// 2 x 36 slots x 64B = 4608 B/wave/step, 5 gld_lds16, 5th exec-masked):
// no wave reads another wave's slab DMA -> slab needs only the wave's own
// counted vmcnt(5) (uniform at every step: retires slab(t)+Bs at dy
// boundaries, slab(t) elsewhere). Barriers: 41 -> 10 (2 per dy, for the
// shared Bs restage only). Waves free-run within each 8-step window.
// Same swizzle (chunk C = (2kh+hi)^((slot>>1)&3), all 8 bank groups),
// same (row,slot,chunk) data semantics as verified R11; compute body
// unchanged (compiler scheduling, proven best of all variants).
// Block 512 thr (8 waves), tile 4x*8y*64z, grid 16*8*2 = 256 = 1/CU.
// LDS 124928 B: Bs 51200 + 8 waves x dbuf 2 x 4608.
// ---------------------------------------------------------------------------
__global__ __launch_bounds__(512, 2) void conv_mfma(
    const unsigned short* __restrict__ xt,   // [b][64][64][68][32] bf16 halo
    const unsigned short* __restrict__ kwb,  // [125][2][64][8]
    const unsigned short* __restrict__ zpg,  // 4 KB zeros
    float* __restrict__ out)                 // [b][32][64][64][64]
{
    extern __shared__ unsigned short smem[];
    char* lds = (char*)smem;

    const int tid = threadIdx.x;
    const int lane = tid & 63;
    const int wv = tid >> 6;                 // 0..7
    const int oyp = wv >> 1, zh = wv & 1;    // oy pair 0..3, z half
    const int x0 = blockIdx.x * 4, y0 = blockIdx.y * 8;
    const int b = blockIdx.z;
    const int l31 = lane & 31, hi = lane >> 5;

    // private slab region: [wbase, wbase + 2*4608) = dbuf of [2 row][36][64B]
    const int wbase = 51200 + wv * 9216;

    // A-read base (buf0, oyi=0); oyi=1: +2304 (imm), buf1: +4608 (imm)
    int abase[5][2];
#pragma unroll
    for (int dz = 0; dz < 5; ++dz) {
        const int sl = l31 + dz;             // local slot 0..35
#pragma unroll
        for (int kh = 0; kh < 2; ++kh) {
            const int C = (kh * 2 + hi) ^ ((sl >> 1) & 3);
            abase[dz][kh] = wbase + sl * 64 + C * 16;
        }
    }
    const int bbase = lane * 16;             // Bs at LDS offset 0

    // private-slab stage precompute: chunk c = p*64 + lane (288 chunks;
    // p==4 active only for lane<32). (row,slot,clog) semantics = R11.
    int srow_[5]; int soff_[5];
#pragma unroll
    for (int p = 0; p < 5; ++p) {
        const int c = p * 64 + lane;
        const int row = (c >= 144) ? 1 : 0;
        const int rem = c - row * 144;
        const int slot = rem >> 2;
        const int clog = (rem & 3) ^ ((slot >> 1) & 3);
        srow_[p] = row;
        soff_[p] = (zh * 32 + slot) * 32 + clog * 8;   // shorts in xt row
    }

    // Bs staging precompute: 3200 chunks, c = tid + k*512
    int bsrc[7];
#pragma unroll
    for (int k = 0; k < 7; ++k) {
        const int c = tid + k * 512;
        const int tp = c >> 7, rem = c & 127;
        const int dxx = tp / 5, dzz = tp - dxx * 5;
        bsrc[k] = (dxx * 25 + dzz) * 128 + rem;
    }

    auto issue_bs = [&](int dy) {
#pragma unroll
        for (int k = 0; k < 7; ++k) {
            const int c0 = wv * 64 + k * 512;   // wave-uniform dest base
            if (c0 < 3200) {
                gld_lds16(kwb + ((size_t)(bsrc[k] + dy * 640)) * 8,
                          lds + c0 * 16);
            }
        }
    };

    // stage THIS wave's slab slice for (dyn, xln) into private buf bufi.
    // Exactly 5 gld_lds16 instructions per wave (uniform vmcnt count).
    auto issue_slab = [&](int dyn, int xln, int bufi) {
        const int xx = x0 + xln - 2;
        const bool xok = ((unsigned)xx < 64u);
        const long long xb = (long long)(b * 64 + xx) * 64;   // row units
        char* dst = lds + wbase + bufi * 4608;
#pragma unroll
        for (int p = 0; p < 5; ++p) {
            const int yy = y0 + oyp * 2 + srow_[p] + dyn - 2;
            const bool ok = xok && ((unsigned)yy < 64u);
            const unsigned short* src = ok
                ? xt + (xb + yy) * 2176 + soff_[p]
                : zpg + lane * 8;
            if (p < 4) {
                gld_lds16(src, dst + p * 1024);
            } else if (lane < 32) {          // chunks 256..287
                gld_lds16(src, dst + 4096);
            }
        }
    };

    f32x16 acc[2][4];
#pragma unroll
    for (int oyi = 0; oyi < 2; ++oyi)
#pragma unroll
        for (int ox = 0; ox < 4; ++ox)
#pragma unroll
            for (int e = 0; e < 16; ++e) acc[oyi][ox][e] = 0.0f;

    // prologue: own slab(0,0) -> buf0, Bs(0); full drain once.
    issue_slab(0, 0, 0);
    issue_bs(0);
    asm volatile("s_waitcnt vmcnt(0)" ::: "memory");
    __syncthreads();

    for (int dy = 0; dy < 5; ++dy) {
#pragma unroll
        for (int xl = 0; xl < 8; ++xl) {
            // top: stage next step's slab into the other private buffer,
            // then the UNIFORM counted wait. At (dy>0, xl==0) the wait also
            // retires this wave's Bs(dy) writes (issued before the newest
            // slab batch) -> barrier after it makes Bs globally ready.
            if (!(dy == 4 && xl == 7)) {
                issue_slab(xl == 7 ? dy + 1 : dy, xl == 7 ? 0 : xl + 1,
                           (xl & 1) ^ 1);
                __builtin_amdgcn_sched_barrier(0);
                asm volatile("s_waitcnt vmcnt(5)" ::: "memory");
            } else {
                asm volatile("s_waitcnt vmcnt(0)" ::: "memory");
            }
            __builtin_amdgcn_sched_barrier(0);
            if (xl == 0 && dy > 0) {
                // barrier2: every wave past its vmcnt -> all Bs(dy) landed
                __builtin_amdgcn_s_barrier();
            }

            // compute from private buf[xl&1] (imm offsets; compiler-
            // scheduled body — best measured of all R1-R9 variants)
            const int boff = (xl & 1) * 4608;
#pragma unroll
            for (int dz = 0; dz < 5; ++dz) {
#pragma unroll
                for (int kh = 0; kh < 2; ++kh) {
                    const short8 a0 = *reinterpret_cast<const short8*>(
                        lds + abase[dz][kh] + boff);
                    const short8 a1 = *reinterpret_cast<const short8*>(
                        lds + abase[dz][kh] + boff + 2304);
#pragma unroll
                    for (int ox = 0; ox < 4; ++ox) {
                        const int dxv = xl - ox;
                        if (dxv < 0 || dxv > 4) continue;
                        const short8 bf = *reinterpret_cast<const short8*>(
                            lds + bbase + (((dxv * 5 + dz) * 2 + kh) << 10));
                        acc[0][ox] = __builtin_amdgcn_mfma_f32_32x32x16_bf16(
                            a0, bf, acc[0][ox], 0, 0, 0);
                        acc[1][ox] = __builtin_amdgcn_mfma_f32_32x32x16_bf16(
                            a1, bf, acc[1][ox], 0, 0, 0);
                    }
                }
            }

            if (xl == 7 && dy < 4) {
                // barrier1: all waves done READING Bs(dy); then each wave
                // issues its share of Bs(dy+1). (Slab needs no barrier.)
                __builtin_amdgcn_s_barrier();
                issue_bs(dy + 1);
                __builtin_amdgcn_sched_barrier(0);
            }
        }
    }

    // epilogue: D lane l: co = l&31, z = zh*32 + rq*8 + (l>>5)*4 + (r&3)
#pragma unroll
    for (int oyi = 0; oyi < 2; ++oyi) {
        const int yy = y0 + oyp * 2 + oyi;
#pragma unroll
        for (int ox = 0; ox < 4; ++ox) {
            float* base = out +
                ((((size_t)b * 32 + l31) * 64 + (x0 + ox)) * 64 + yy) * 64 +
                zh * 32 + hi * 4;
#pragma unroll
            for (int rq = 0; rq < 4; ++rq) {
                f32x4 v = { acc[oyi][ox][rq * 4 + 0], acc[oyi][ox][rq * 4 + 1],
                            acc[oyi][ox][rq * 4 + 2], acc[oyi][ox][rq * 4 + 3] };
                *reinterpret_cast<f32x4*>(base + rq * 8) = v;
            }
        }
    }
}

// ---------------------------------------------------------------------------
extern "C" void kernel_launch(void* const* d_in, const int* in_sizes, int n_in,
                              void* d_out, int out_size, void* d_ws, size_t ws_size,
                              hipStream_t stream) {
    const float* x      = (const float*)d_in[0];
    const float* weight = (const float*)d_in[1];
    const float* w_sc0  = (const float*)d_in[2];
    const float* w_sc1  = (const float*)d_in[3];
    float* out = (float*)d_out;

    char* ws = (char*)d_ws;
    unsigned short* xt  = (unsigned short*)ws;                 // 35,651,584 B
    unsigned short* kwb = (unsigned short*)(ws + 35651584);    //    256,000 B
    unsigned short* zpg = (unsigned short*)(ws + 35907584);    //      4,096 B

    (void)hipFuncSetAttribute((const void*)conv_mfma,
                              hipFuncAttributeMaxDynamicSharedMemorySize,
                              124928);

    hipLaunchKernelGGL(build_pack, dim3(NTAP), dim3(128), 0, stream,
                       weight, w_sc0, w_sc1, kwb, (float4*)zpg);
    hipLaunchKernelGGL(xpose, dim3(64, 64, 2), dim3(256), 0, stream, x, xt);
    hipLaunchKernelGGL(conv_mfma, dim3(16, 8, 2), dim3(512), 124928, stream,
                       xt, kwb, zpg, out);
}